// Round 9
// baseline (208.948 us; speedup 1.0000x reference)
//
#include <hip/hip_runtime.h>

#define THREADS 256
#define B_DIM   4
#define H_DIM   1024
#define L_DIM   4096
#define NFFT    4096      // half-length complex FFT size (real n = 8192)
#define PI_F     3.14159265358979323846f
#define TWO_PI_F 6.28318530717958647692f
#define T1_N    3840      // 15 x 256 level-1 twiddles
#define T2_N    240       // 15 x 16  level-2 twiddles

__device__ __forceinline__ float2 cmulf(float2 a, float2 b) {
    return make_float2(a.x*b.x - a.y*b.y, a.x*b.y + a.y*b.x);
}
// a * conj(b) — same op count as cmulf
__device__ __forceinline__ float2 cmulcf(float2 a, float2 b) {
    return make_float2(a.x*b.x + a.y*b.y, a.y*b.x - a.x*b.y);
}
__device__ __forceinline__ float2 caddf(float2 a, float2 b){ return make_float2(a.x+b.x, a.y+b.y); }
__device__ __forceinline__ float2 csubf(float2 a, float2 b){ return make_float2(a.x-b.x, a.y-b.y); }

// XOR swizzle: bank-pair = d2^d1^d0 -> ~4 lanes/bank-pair (b64 floor) on all patterns
__device__ __forceinline__ int swz(int i) { return i ^ ((i>>4)&15) ^ ((i>>8)&15); }

// base-16 digit reversal of a 12-bit index
__device__ __forceinline__ int drev12(int x) {
    return ((x & 15) << 8) | (x & 0xF0) | (x >> 8);
}

// w[kk] = e^{i*base*kk}, kk=1..15, via 1 sincos + squaring tree (14 cmul)
__device__ __forceinline__ void make_tw(float base, float2 w[16]) {
    float sn, cs; __sincosf(base, &sn, &cs);
    w[1]  = make_float2(cs, sn);
    w[2]  = cmulf(w[1], w[1]);
    w[3]  = cmulf(w[2], w[1]);
    w[4]  = cmulf(w[2], w[2]);
    w[5]  = cmulf(w[4], w[1]);
    w[6]  = cmulf(w[4], w[2]);
    w[7]  = cmulf(w[4], w[3]);
    w[8]  = cmulf(w[4], w[4]);
    w[9]  = cmulf(w[8], w[1]);
    w[10] = cmulf(w[8], w[2]);
    w[11] = cmulf(w[8], w[3]);
    w[12] = cmulf(w[8], w[4]);
    w[13] = cmulf(w[8], w[5]);
    w[14] = cmulf(w[8], w[6]);
    w[15] = cmulf(w[8], w[7]);
}

// W16^q = e^{SGN*2pi*i*q/16}
__device__ __forceinline__ float2 w16c(int q, float s) {
    constexpr float C[8] = {1.f, 0.9238795325f, 0.7071067812f, 0.3826834324f,
                            0.f, -0.3826834324f, -0.7071067812f, -0.9238795325f};
    constexpr float S[8] = {0.f, 0.3826834324f, 0.7071067812f, 0.9238795325f,
                            1.f, 0.9238795325f, 0.7071067812f, 0.3826834324f};
    return make_float2(C[q], s*S[q]);
}

template<int SGN>
__device__ __forceinline__ float2 twq(float2 d, int q) {
    if (q == 0) return d;
    if (q == 4) return make_float2((float)(-SGN)*d.y, (float)SGN*d.x);
    return cmulf(d, w16c(q, (float)SGN));
}

// Radix-2 DIF 16-pt DFT: natural-order input, bit-reversed output (bin k at reg REV4[k]).
template<int SGN, bool HZ>
__device__ __forceinline__ void dif16(float2 v[16]) {
    if (HZ) {
        #pragma unroll
        for (int i = 0; i < 8; ++i) {
            float2 a = v[i];
            v[i+8] = twq<SGN>(a, i);
        }
    } else {
        #pragma unroll
        for (int i = 0; i < 8; ++i) {
            float2 a = v[i], b = v[i+8];
            v[i]   = caddf(a,b);
            v[i+8] = twq<SGN>(csubf(a,b), i);
        }
    }
    #pragma unroll
    for (int h = 4; h >= 1; h >>= 1) {
        const int step = 8 / h;
        #pragma unroll
        for (int g = 0; g < 16; g += 2*h) {
            #pragma unroll
            for (int i = 0; i < h; ++i) {
                float2 a = v[g+i], b = v[g+i+h];
                v[g+i]   = caddf(a,b);
                v[g+i+h] = twq<SGN>(csubf(a,b), i*step);
            }
        }
    }
}

// Radix-2 DIT 16-pt DFT: bit-reversed input, natural-order output.
template<int SGN>
__device__ __forceinline__ void dit16(float2 v[16]) {
    #pragma unroll
    for (int h = 1; h <= 8; h <<= 1) {
        const int step = 8 / h;
        #pragma unroll
        for (int g = 0; g < 16; g += 2*h) {
            #pragma unroll
            for (int i = 0; i < h; ++i) {
                float2 a = v[g+i];
                float2 b = twq<SGN>(v[g+i+h], i*step);
                v[g+i]   = caddf(a,b);
                v[g+i+h] = csubf(a,b);
            }
        }
    }
}

// Forward FFT levels 1+2 (of 3) of a zero-padded packed real row into LDS Z.
// Leaves level-2 results in LDS (swizzled), syncs before return.
__device__ __forceinline__ void fwd_fft_12(const float2* __restrict__ src, float2* Z, int t) {
    constexpr int REV4[16] = {0,8,4,12,2,10,6,14,1,9,5,13,3,11,7,15};
    float2 v[16], w[16];
    #pragma unroll
    for (int r = 0; r < 8; ++r) v[r] = src[256*r + t];
    dif16<-1, true>(v);
    make_tw(-TWO_PI_F * (float)t / (float)NFFT, w);
    #pragma unroll
    for (int kk = 1; kk < 16; ++kk) v[REV4[kk]] = cmulf(v[REV4[kk]], w[kk]);
    #pragma unroll
    for (int kk = 0; kk < 16; ++kk) Z[swz(256*kk + t)] = v[REV4[kk]];
    __syncthreads();

    const int k1 = t >> 4, m = t & 15;
    const int rb = 256*k1 + m;
    #pragma unroll
    for (int r = 0; r < 16; ++r) v[r] = Z[swz(rb + 16*r)];
    dif16<-1,false>(v);
    make_tw(-TWO_PI_F * (float)m / 256.f, w);
    #pragma unroll
    for (int kk = 1; kk < 16; ++kk) v[REV4[kk]] = cmulf(v[REV4[kk]], w[kk]);
    #pragma unroll
    for (int kk = 0; kk < 16; ++kk) Z[swz(rb + 16*kk)] = v[REV4[kk]];
    __syncthreads();
}

// Full forward 3-level FFT (old-path helper): position p holds bin drev(p), swizzled.
__device__ __forceinline__ void fwd_fft_row(const float2* __restrict__ src, float2* Z, int t) {
    constexpr int REV4[16] = {0,8,4,12,2,10,6,14,1,9,5,13,3,11,7,15};
    fwd_fft_12(src, Z, t);
    float2 v[16];
    const int b3 = t << 4;
    #pragma unroll
    for (int r = 0; r < 16; ++r) v[r] = Z[swz(b3 + r)];
    dif16<-1,false>(v);
    #pragma unroll
    for (int kk = 0; kk < 16; ++kk) Z[swz(b3 + kk)] = v[REV4[kk]];
}

// digit-reversed (base-16) position of bin j, swizzled
__device__ __forceinline__ int binpos(int j) {
    return swz( ((j&15)<<8) | (((j>>4)&15)<<4) | (j>>8) );
}

// ================= PQ PATH =================
// Zy[j] = P_j * Zx[j] + Q_j * conj(Zx[4096-j]);  1/NFFT folded in.
// Layout: PQ[hh][kk][t]  (kk-major, thread-minor) -> every ld/st lane-coalesced.
// Entry (kk,t) holds P,Q for spectrum position p = t*16+kk (digit-reversed slot).
// Twt (optional): T1[kk-1][t] = e^{-2pi i t kk/4096} (3840), then
//                 T2[kk-1][m] = e^{-2pi i m kk/256}  (240). Written by block 0.

__global__ __launch_bounds__(THREADS, 3)
void kpq_kernel(const float* __restrict__ k, float4* __restrict__ PQ_all,
                float2* __restrict__ Twt) {
    __shared__ float2 Zk[NFFT];
    constexpr int REV4[16] = {0,8,4,12,2,10,6,14,1,9,5,13,3,11,7,15};
    const int t  = threadIdx.x;
    const int hh = blockIdx.x;
    const float2* kp = (const float2*)(k + (size_t)hh * L_DIM);

    // block 0 also fills the twiddle tables (independent of its FFT work)
    if (Twt != nullptr && hh == 0) {
        #pragma unroll
        for (int kk = 1; kk < 16; ++kk) {
            float sn, cs; __sincosf(-TWO_PI_F * (float)(t*kk) / (float)NFFT, &sn, &cs);
            Twt[(kk-1)*256 + t] = make_float2(cs, sn);
        }
        if (t < T2_N) {
            int kk = t / 16 + 1, m = t & 15;
            float sn, cs; __sincosf(-TWO_PI_F * (float)(m*kk) / 256.f, &sn, &cs);
            Twt[T1_N + t] = make_float2(cs, sn);
        }
    }

    fwd_fft_12(kp, Zk, t);

    // forward level 3 in regs, publish for partner exchange
    const int b3 = t << 4;
    float2 v[16];
    #pragma unroll
    for (int r = 0; r < 16; ++r) v[r] = Zk[swz(b3 + r)];
    dif16<-1,false>(v);
    #pragma unroll
    for (int kk = 0; kk < 16; ++kk) Zk[swz(b3 + kk)] = v[REV4[kk]];
    __syncthreads();

    // own bins: j = kk*256 + rdig ; partner position = (C - kk) & M
    const int j1 = t & 15, j0 = t >> 4;
    const int rdig = (j1 << 4) | j0;
    const int C = t ? drev12(NFFT - rdig) : 16;
    const int M = t ? (NFFT - 1) : 15;

    float4* PQh = PQ_all + (size_t)hh * NFFT;
    const float sc = 1.f / (float)NFFT;

    // w(j) = e^{-i*pi*rdig/4096} * W16^kk  (1 sincos + chained cmul)
    float sn0, cs0; __sincosf(-PI_F * (float)rdig / (float)NFFT, &sn0, &cs0);
    float2 wj = make_float2(cs0, sn0);
    const float2 W16 = make_float2(0.98078528040323044913f, -0.19509032201612826785f);

    #pragma unroll
    for (int kk = 0; kk < 16; ++kk) {
        float2 Zj = v[REV4[kk]];
        float2 zm = Zk[swz((C - kk) & M)];
        float2 Zmc = make_float2(zm.x, -zm.y);

        const float c = wj.x, d = wj.y;             // w = c + i d
        float2 u1 = make_float2(1.f + d, -c);       // 1 - i w
        float2 u2 = make_float2(1.f - d,  c);       // 1 + i w
        float2 A   = caddf(cmulf(u1, Zj), cmulf(u2, Zmc));
        float2 Amc = caddf(cmulf(u2, Zj), cmulf(u1, Zmc));
        float2 P = make_float2(0.25f*((1.f+d)*A.x + (1.f-d)*Amc.x),
                               0.25f*((1.f+d)*A.y + (1.f-d)*Amc.y));
        float2 dK = csubf(A, Amc);
        float2 Q = make_float2(-0.25f*c*dK.y, 0.25f*c*dK.x);
        PQh[(kk << 8) | t] = make_float4(P.x*sc, P.y*sc, Q.x*sc, Q.y*sc);

        wj = cmulf(wj, W16);
    }
}

// Single-row conv with table twiddles: removes 4 per-thread make_tw
// (4 sincos + 56 serial cmul, ~250 VALU + ~240 cycles unhidden chain latency),
// replaced by L2-resident coalesced loads issued behind barriers.
__global__ __launch_bounds__(THREADS, 2)
void conv_pq_tab_kernel(const float* __restrict__ x, const float4* __restrict__ PQ_all,
                        const float2* __restrict__ Twt, float* __restrict__ out) {
    __shared__ float2 Zx[NFFT];
    constexpr int REV4[16] = {0,8,4,12,2,10,6,14,1,9,5,13,3,11,7,15};

    const int t  = threadIdx.x;
    const int wg = blockIdx.x;
    const int hh = wg & (H_DIM - 1);
    const int b  = wg >> 10;
    const int m  = t & 15;

    const float2* xp = (const float2*)(x + ((size_t)(b*H_DIM + hh)) * L_DIM);
    const float2* T1 = Twt;
    const float2* T2 = Twt + T1_N;

    // ---- forward level 1: x loads + T1 row loads (all independent) ----
    float2 v[16], w[16];
    #pragma unroll
    for (int r = 0; r < 8; ++r) v[r] = xp[256*r + t];
    #pragma unroll
    for (int kk = 1; kk < 16; ++kk) w[kk] = T1[(kk-1)*256 + t];
    dif16<-1, true>(v);
    #pragma unroll
    for (int kk = 1; kk < 16; ++kk) v[REV4[kk]] = cmulf(v[REV4[kk]], w[kk]);
    #pragma unroll
    for (int kk = 0; kk < 16; ++kk) Zx[swz(256*kk + t)] = v[REV4[kk]];
    // prefetch T2 row before the barrier (L2, independent of LDS)
    #pragma unroll
    for (int kk = 1; kk < 16; ++kk) w[kk] = T2[(kk-1)*16 + m];
    __syncthreads();

    // ---- forward level 2 ----
    const int k1 = t >> 4;
    const int rb = 256*k1 + m;
    #pragma unroll
    for (int r = 0; r < 16; ++r) v[r] = Zx[swz(rb + 16*r)];
    dif16<-1,false>(v);
    #pragma unroll
    for (int kk = 1; kk < 16; ++kk) v[REV4[kk]] = cmulf(v[REV4[kk]], w[kk]);
    #pragma unroll
    for (int kk = 0; kk < 16; ++kk) Zx[swz(rb + 16*kk)] = v[REV4[kk]];
    __syncthreads();

    // ---- forward level 3 in regs + PQ prefetch ----
    const int b3 = t << 4;
    #pragma unroll
    for (int r = 0; r < 16; ++r) v[r] = Zx[swz(b3 + r)];
    dif16<-1,false>(v);

    const float4* PQh = PQ_all + (size_t)hh * NFFT;
    float4 pq[16];
    #pragma unroll
    for (int kk = 0; kk < 16; ++kk) pq[kk] = PQh[(kk << 8) | t];

    #pragma unroll
    for (int kk = 0; kk < 16; ++kk) Zx[swz(b3 + kk)] = v[REV4[kk]];
    __syncthreads();

    // ---- combine + inverse level A entirely in registers ----
    const int j1 = t & 15, j0 = t >> 4;
    const int rdig = (j1 << 4) | j0;
    const int C = t ? drev12(NFFT - rdig) : 16;
    const int M = t ? (NFFT - 1) : 15;

    float2 vy[16];
    #pragma unroll
    for (int kk = 0; kk < 16; ++kk) {
        float2 Zj = v[REV4[kk]];
        float2 zm = Zx[swz((C - kk) & M)];
        float2 P = make_float2(pq[kk].x, pq[kk].y);
        float2 Q = make_float2(pq[kk].z, pq[kk].w);
        float2 r1 = cmulf(P, Zj);
        float2 r2 = make_float2(Q.x*zm.x + Q.y*zm.y, Q.y*zm.x - Q.x*zm.y);
        vy[REV4[kk]] = caddf(r1, r2);
    }
    dit16<1>(vy);
    // prefetch levB twiddles (conj of T2 row) while waiting
    #pragma unroll
    for (int kk = 1; kk < 16; ++kk) w[kk] = T2[(kk-1)*16 + m];
    __syncthreads();                    // all partner reads done before overwrite
    #pragma unroll
    for (int mm = 0; mm < 16; ++mm) Zx[swz(b3 + mm)] = vy[mm];
    __syncthreads();

    // ---- inverse level B: untwiddle (conj table) then iDFT over stride-16 ----
    float2 vx[16];
    #pragma unroll
    for (int kk = 0; kk < 16; ++kk) {
        float2 val = Zx[swz(rb + 16*kk)];
        if (kk > 0) val = cmulcf(val, w[kk]);
        vx[REV4[kk]] = val;
    }
    dit16<1>(vx);
    #pragma unroll
    for (int r = 0; r < 16; ++r) Zx[swz(rb + 16*r)] = vx[r];
    // prefetch levC twiddles (conj of T1 row)
    #pragma unroll
    for (int kk = 1; kk < 16; ++kk) w[kk] = T1[(kk-1)*256 + t];
    __syncthreads();

    // ---- inverse level C: untwiddle (conj table), iDFT, store 4096 reals ----
    #pragma unroll
    for (int kk = 0; kk < 16; ++kk) {
        float2 val = Zx[swz(256*kk + t)];
        if (kk > 0) val = cmulcf(val, w[kk]);
        vx[REV4[kk]] = val;
    }
    dit16<1>(vx);
    float2* op = (float2*)(out + ((size_t)(b*H_DIM + hh)) * L_DIM);
    #pragma unroll
    for (int n1 = 0; n1 < 8; ++n1) {
        op[256*n1 + t] = vx[n1];        // 1/NFFT folded into P,Q
    }
}

// Single-row conv, sincos twiddles (R8-verified, 81 us): tier without table space.
__global__ __launch_bounds__(THREADS, 2)
void conv_pq_kernel(const float* __restrict__ x, const float4* __restrict__ PQ_all,
                    float* __restrict__ out) {
    __shared__ float2 Zx[NFFT];
    constexpr int REV4[16] = {0,8,4,12,2,10,6,14,1,9,5,13,3,11,7,15};

    const int t  = threadIdx.x;
    const int wg = blockIdx.x;
    const int hh = wg & (H_DIM - 1);
    const int b  = wg >> 10;

    const float2* xp = (const float2*)(x + ((size_t)(b*H_DIM + hh)) * L_DIM);

    fwd_fft_12(xp, Zx, t);

    const float4* PQh = PQ_all + (size_t)hh * NFFT;
    float4 pq[16];
    #pragma unroll
    for (int kk = 0; kk < 16; ++kk) pq[kk] = PQh[(kk << 8) | t];

    const int b3 = t << 4;
    float2 v[16];
    #pragma unroll
    for (int r = 0; r < 16; ++r) v[r] = Zx[swz(b3 + r)];
    dif16<-1,false>(v);
    #pragma unroll
    for (int kk = 0; kk < 16; ++kk) Zx[swz(b3 + kk)] = v[REV4[kk]];
    __syncthreads();

    const int j1 = t & 15, j0 = t >> 4;
    const int rdig = (j1 << 4) | j0;
    const int C = t ? drev12(NFFT - rdig) : 16;
    const int M = t ? (NFFT - 1) : 15;

    float2 vy[16];
    #pragma unroll
    for (int kk = 0; kk < 16; ++kk) {
        float2 Zj = v[REV4[kk]];
        float2 zm = Zx[swz((C - kk) & M)];
        float2 P = make_float2(pq[kk].x, pq[kk].y);
        float2 Q = make_float2(pq[kk].z, pq[kk].w);
        float2 r1 = cmulf(P, Zj);
        float2 r2 = make_float2(Q.x*zm.x + Q.y*zm.y, Q.y*zm.x - Q.x*zm.y);
        vy[REV4[kk]] = caddf(r1, r2);
    }
    dit16<1>(vy);
    __syncthreads();
    #pragma unroll
    for (int mm = 0; mm < 16; ++mm) Zx[swz(b3 + mm)] = vy[mm];
    __syncthreads();

    float2 vx[16], w[16];
    const int k1 = t >> 4, m = t & 15;
    const int rb = 256*k1 + m;
    make_tw(TWO_PI_F * (float)m / 256.f, w);
    #pragma unroll
    for (int kk = 0; kk < 16; ++kk) {
        float2 val = Zx[swz(rb + 16*kk)];
        if (kk > 0) val = cmulf(val, w[kk]);
        vx[REV4[kk]] = val;
    }
    dit16<1>(vx);
    #pragma unroll
    for (int r = 0; r < 16; ++r) Zx[swz(rb + 16*r)] = vx[r];
    __syncthreads();

    make_tw(TWO_PI_F * (float)t / (float)NFFT, w);
    #pragma unroll
    for (int kk = 0; kk < 16; ++kk) {
        float2 val = Zx[swz(256*kk + t)];
        if (kk > 0) val = cmulf(val, w[kk]);
        vx[REV4[kk]] = val;
    }
    dit16<1>(vx);
    float2* op = (float2*)(out + ((size_t)(b*H_DIM + hh)) * L_DIM);
    #pragma unroll
    for (int n1 = 0; n1 < 8; ++n1) {
        op[256*n1 + t] = vx[n1];
    }
}

// ================= OLD PATH (32 MB ws): natural-order Kf =================
__global__ __launch_bounds__(THREADS, 4)
void kfft_kernel(const float* __restrict__ k, float2* __restrict__ Kf_all) {
    __shared__ float2 Zk[NFFT];
    const int t  = threadIdx.x;
    const int hh = blockIdx.x;
    const float2* kp = (const float2*)(k + (size_t)hh * L_DIM);

    fwd_fft_row(kp, Zk, t);
    __syncthreads();

    float2* Kf = Kf_all + (size_t)hh * NFFT;
    #pragma unroll
    for (int s = 0; s < 8; ++s) {
        int j = t + 256*s;
        if (j == 0) {
            float2 zk = Zk[0];
            Kf[0] = make_float2(zk.x + zk.y, zk.x - zk.y);
            float2 zk2 = Zk[swz(8)];
            Kf[2048] = make_float2(zk2.x, -zk2.y);
        } else {
            int jm = NFFT - j;
            float2 zkj = Zk[binpos(j)], zkm = Zk[binpos(jm)];
            float sn, cs; __sincosf(-PI_F * (float)j / (float)NFFT, &sn, &cs);
            float2 w = make_float2(cs, sn);
            float2 Ke = make_float2(0.5f*(zkj.x + zkm.x), 0.5f*(zkj.y - zkm.y));
            float2 dk = make_float2(zkj.x - zkm.x, zkj.y + zkm.y);
            float2 Ko = make_float2(0.5f*dk.y, -0.5f*dk.x);
            float2 tk = cmulf(w, Ko);
            Kf[j]  = caddf(Ke, tk);
            Kf[jm] = make_float2(Ke.x - tk.x, -(Ke.y - tk.y));
        }
    }
}

__global__ __launch_bounds__(THREADS, 4)
void conv_main_kernel(const float* __restrict__ x, const float2* __restrict__ Kf_all,
                      float* __restrict__ out) {
    __shared__ float2 Zx[NFFT];
    constexpr int REV4[16] = {0,8,4,12,2,10,6,14,1,9,5,13,3,11,7,15};

    const int t  = threadIdx.x;
    const int wg = blockIdx.x;
    const int hh = wg & (H_DIM - 1);
    const int b  = wg >> 10;

    const float2* xp = (const float2*)(x + ((size_t)(b*H_DIM + hh)) * L_DIM);
    const float2* Kf = Kf_all + (size_t)hh * NFFT;

    fwd_fft_row(xp, Zx, t);

    float2 kfj[8], kfm[8], kf2;
    #pragma unroll
    for (int s = 0; s < 8; ++s) {
        int j = t + 256*s;
        kfj[s] = Kf[j];
        kfm[s] = Kf[(NFFT - j) & (NFFT - 1)];
    }
    kf2 = Kf[2048];
    __syncthreads();

    #pragma unroll
    for (int s = 0; s < 8; ++s) {
        int j = t + 256*s;
        if (j == 0) {
            float2 zx = Zx[0];
            float ax0 = zx.x + zx.y, axM = zx.x - zx.y;
            float y0 = ax0 * kfj[0].x, yM = axM * kfj[0].y;
            Zx[0] = make_float2(0.5f*(y0 + yM), 0.5f*(y0 - yM));
            int p2 = swz(8);
            float2 zx2 = Zx[p2];
            Zx[p2] = cmulf(zx2, make_float2(kf2.x, -kf2.y));
        } else {
            int jm = NFFT - j;
            int pj = binpos(j), pm = binpos(jm);
            float2 zxj = Zx[pj], zxm = Zx[pm];

            float sn, cs; __sincosf(-PI_F * (float)j / (float)NFFT, &sn, &cs);
            float2 w = make_float2(cs, sn);

            float2 Xe = make_float2(0.5f*(zxj.x + zxm.x), 0.5f*(zxj.y - zxm.y));
            float2 dx = make_float2(zxj.x - zxm.x, zxj.y + zxm.y);
            float2 Xo = make_float2(0.5f*dx.y, -0.5f*dx.x);
            float2 tx = cmulf(w, Xo);
            float2 Axj = caddf(Xe, tx);
            float2 Axm = make_float2(Xe.x - tx.x, -(Xe.y - tx.y));

            float2 Yj = cmulf(Axj, kfj[s]);
            float2 Ym = cmulf(Axm, kfm[s]);

            float2 u  = make_float2(0.5f*(Yj.x + Ym.x), 0.5f*(Yj.y - Ym.y));
            float2 dd = make_float2(Yj.x - Ym.x, Yj.y + Ym.y);
            float2 wc = make_float2(w.x, -w.y);
            float2 vv = cmulf(wc, dd);
            vv.x *= 0.5f; vv.y *= 0.5f;
            Zx[pj] = make_float2(u.x - vv.y, u.y + vv.x);
            Zx[pm] = make_float2(u.x + vv.y, -(u.y - vv.x));
        }
    }
    __syncthreads();

    float2 vx[16], w[16];
    const int k1 = t >> 4, m = t & 15;
    const int rb = 256*k1 + m;
    const int b3 = t << 4;

    #pragma unroll
    for (int r = 0; r < 16; ++r) vx[REV4[r]] = Zx[swz(b3 + r)];
    dit16<1>(vx);
    #pragma unroll
    for (int mm = 0; mm < 16; ++mm) Zx[swz(b3 + mm)] = vx[mm];
    __syncthreads();

    make_tw(TWO_PI_F * (float)m / 256.f, w);
    #pragma unroll
    for (int kk = 0; kk < 16; ++kk) {
        float2 val = Zx[swz(rb + 16*kk)];
        if (kk > 0) val = cmulf(val, w[kk]);
        vx[REV4[kk]] = val;
    }
    dit16<1>(vx);
    #pragma unroll
    for (int r = 0; r < 16; ++r) Zx[swz(rb + 16*r)] = vx[r];
    __syncthreads();

    make_tw(TWO_PI_F * (float)t / (float)NFFT, w);
    #pragma unroll
    for (int kk = 0; kk < 16; ++kk) {
        float2 val = Zx[swz(256*kk + t)];
        if (kk > 0) val = cmulf(val, w[kk]);
        vx[REV4[kk]] = val;
    }
    dit16<1>(vx);
    float2* op = (float2*)(out + ((size_t)(b*H_DIM + hh)) * L_DIM);
    const float sc = 1.f / (float)NFFT;
    #pragma unroll
    for (int n1 = 0; n1 < 8; ++n1) {
        float2 z = vx[n1];
        op[256*n1 + t] = make_float2(z.x*sc, z.y*sc);
    }
}

// ---------------- Fallback (R2, known-good): used if ws too small ----------------
__global__ __launch_bounds__(THREADS, 2)
void fftconv_fallback(const float* __restrict__ x, const float* __restrict__ k,
                      float* __restrict__ out) {
    __shared__ float2 Zx[NFFT];
    __shared__ float2 Zk[NFFT];
    constexpr int REV4[16] = {0,8,4,12,2,10,6,14,1,9,5,13,3,11,7,15};

    const int t  = threadIdx.x;
    const int wg = blockIdx.x;
    const int hh = wg & (H_DIM - 1);
    const int b  = wg >> 10;

    const float2* xp = (const float2*)(x + ((size_t)(b*H_DIM + hh)) * L_DIM);
    const float2* kp = (const float2*)(k + (size_t)hh * L_DIM);

    fwd_fft_row(xp, Zx, t);
    __syncthreads();
    fwd_fft_row(kp, Zk, t);
    __syncthreads();

    #pragma unroll
    for (int s = 0; s < 8; ++s) {
        int j = t + 256*s;
        if (j == 0) {
            float2 zx = Zx[0], zk = Zk[0];
            float ax0 = zx.x + zx.y, axM = zx.x - zx.y;
            float ak0 = zk.x + zk.y, akM = zk.x - zk.y;
            float y0 = ax0*ak0, yM = axM*akM;
            Zx[0] = make_float2(0.5f*(y0+yM), 0.5f*(y0-yM));
            int p2 = swz(8);
            Zx[p2] = cmulf(Zx[p2], Zk[p2]);
        } else {
            int jm = NFFT - j;
            int pj = binpos(j), pm = binpos(jm);
            float2 zxj = Zx[pj], zxm = Zx[pm];
            float2 zkj = Zk[pj], zkm = Zk[pm];
            float sn, cs; __sincosf(-PI_F * (float)j / (float)NFFT, &sn, &cs);
            float2 w = make_float2(cs, sn);
            float2 Xe = make_float2(0.5f*(zxj.x + zxm.x), 0.5f*(zxj.y - zxm.y));
            float2 dx = make_float2(zxj.x - zxm.x, zxj.y + zxm.y);
            float2 Xo = make_float2(0.5f*dx.y, -0.5f*dx.x);
            float2 tx = cmulf(w, Xo);
            float2 Axj = caddf(Xe, tx);
            float2 Axm = make_float2(Xe.x - tx.x, -(Xe.y - tx.y));
            float2 Ke = make_float2(0.5f*(zkj.x + zkm.x), 0.5f*(zkj.y - zkm.y));
            float2 dk = make_float2(zkj.x - zkm.x, zkj.y + zkm.y);
            float2 Ko = make_float2(0.5f*dk.y, -0.5f*dk.x);
            float2 tk = cmulf(w, Ko);
            float2 Akj = caddf(Ke, tk);
            float2 Akm = make_float2(Ke.x - tk.x, -(Ke.y - tk.y));
            float2 Yj = cmulf(Axj, Akj);
            float2 Ym = cmulf(Axm, Akm);
            float2 u  = make_float2(0.5f*(Yj.x + Ym.x), 0.5f*(Yj.y - Ym.y));
            float2 dd = make_float2(Yj.x - Ym.x, Yj.y + Ym.y);
            float2 wc = make_float2(w.x, -w.y);
            float2 vv = cmulf(wc, dd);
            vv.x *= 0.5f; vv.y *= 0.5f;
            Zx[pj] = make_float2(u.x - vv.y, u.y + vv.x);
            Zx[pm] = make_float2(u.x + vv.y, -(u.y - vv.x));
        }
    }
    __syncthreads();

    float2 vx[16], w[16];
    const int k1 = t >> 4, m = t & 15;
    const int rb = 256*k1 + m;
    const int b3 = t << 4;

    #pragma unroll
    for (int r = 0; r < 16; ++r) vx[REV4[r]] = Zx[swz(b3 + r)];
    dit16<1>(vx);
    #pragma unroll
    for (int mm = 0; mm < 16; ++mm) Zx[swz(b3 + mm)] = vx[mm];
    __syncthreads();

    make_tw(TWO_PI_F * (float)m / 256.f, w);
    #pragma unroll
    for (int kk = 0; kk < 16; ++kk) {
        float2 val = Zx[swz(rb + 16*kk)];
        if (kk > 0) val = cmulf(val, w[kk]);
        vx[REV4[kk]] = val;
    }
    dit16<1>(vx);
    #pragma unroll
    for (int r = 0; r < 16; ++r) Zx[swz(rb + 16*r)] = vx[r];
    __syncthreads();

    make_tw(TWO_PI_F * (float)t / (float)NFFT, w);
    #pragma unroll
    for (int kk = 0; kk < 16; ++kk) {
        float2 val = Zx[swz(256*kk + t)];
        if (kk > 0) val = cmulf(val, w[kk]);
        vx[REV4[kk]] = val;
    }
    dit16<1>(vx);
    float2* op = (float2*)(out + ((size_t)(b*H_DIM + hh)) * L_DIM);
    const float sc = 1.f / (float)NFFT;
    #pragma unroll
    for (int n1 = 0; n1 < 8; ++n1) {
        float2 z = vx[n1];
        op[256*n1 + t] = make_float2(z.x*sc, z.y*sc);
    }
}

extern "C" void kernel_launch(void* const* d_in, const int* in_sizes, int n_in,
                              void* d_out, int out_size, void* d_ws, size_t ws_size,
                              hipStream_t stream) {
    const float* x = (const float*)d_in[0];
    const float* k = (const float*)d_in[1];
    float* out = (float*)d_out;
    const size_t needPQ = (size_t)H_DIM * NFFT * sizeof(float4);          // 64 MB
    const size_t needTW = (size_t)(T1_N + T2_N) * sizeof(float2);         // ~32 KB
    const size_t needKf = (size_t)H_DIM * NFFT * sizeof(float2);          // 32 MB
    if (ws_size >= needPQ + needTW) {
        float4* PQ = (float4*)d_ws;
        float2* Twt = (float2*)((char*)d_ws + needPQ);
        kpq_kernel<<<dim3(H_DIM), dim3(THREADS), 0, stream>>>(k, PQ, Twt);
        conv_pq_tab_kernel<<<dim3(B_DIM * H_DIM), dim3(THREADS), 0, stream>>>(x, PQ, Twt, out);
    } else if (ws_size >= needPQ) {
        float4* PQ = (float4*)d_ws;
        kpq_kernel<<<dim3(H_DIM), dim3(THREADS), 0, stream>>>(k, PQ, nullptr);
        conv_pq_kernel<<<dim3(B_DIM * H_DIM), dim3(THREADS), 0, stream>>>(x, PQ, out);
    } else if (ws_size >= needKf) {
        float2* Kf = (float2*)d_ws;
        kfft_kernel<<<dim3(H_DIM), dim3(THREADS), 0, stream>>>(k, Kf);
        conv_main_kernel<<<dim3(B_DIM * H_DIM), dim3(THREADS), 0, stream>>>(x, Kf, out);
    } else {
        fftconv_fallback<<<dim3(B_DIM * H_DIM), dim3(THREADS), 0, stream>>>(x, k, out);
    }
}

// Round 10
// 174.211 us; speedup vs baseline: 1.1994x; 1.1994x over previous
//
#include <hip/hip_runtime.h>

#define THREADS 256
#define B_DIM   4
#define H_DIM   1024
#define L_DIM   4096
#define NFFT    4096      // half-length complex FFT size (real n = 8192)
#define PI_F     3.14159265358979323846f
#define TWO_PI_F 6.28318530717958647692f

__device__ __forceinline__ float2 cmulf(float2 a, float2 b) {
    return make_float2(a.x*b.x - a.y*b.y, a.x*b.y + a.y*b.x);
}
__device__ __forceinline__ float2 caddf(float2 a, float2 b){ return make_float2(a.x+b.x, a.y+b.y); }
__device__ __forceinline__ float2 csubf(float2 a, float2 b){ return make_float2(a.x-b.x, a.y-b.y); }

// XOR swizzle: bank-pair = d2^d1^d0 -> ~4 lanes/bank-pair (b64 floor) on all patterns
__device__ __forceinline__ int swz(int i) { return i ^ ((i>>4)&15) ^ ((i>>8)&15); }

// w[kk] = e^{i*base*kk}, kk=1..15, via 1 sincos + squaring tree (14 cmul)
__device__ __forceinline__ void make_tw(float base, float2 w[16]) {
    float sn, cs; __sincosf(base, &sn, &cs);
    w[1]  = make_float2(cs, sn);
    w[2]  = cmulf(w[1], w[1]);
    w[3]  = cmulf(w[2], w[1]);
    w[4]  = cmulf(w[2], w[2]);
    w[5]  = cmulf(w[4], w[1]);
    w[6]  = cmulf(w[4], w[2]);
    w[7]  = cmulf(w[4], w[3]);
    w[8]  = cmulf(w[4], w[4]);
    w[9]  = cmulf(w[8], w[1]);
    w[10] = cmulf(w[8], w[2]);
    w[11] = cmulf(w[8], w[3]);
    w[12] = cmulf(w[8], w[4]);
    w[13] = cmulf(w[8], w[5]);
    w[14] = cmulf(w[8], w[6]);
    w[15] = cmulf(w[8], w[7]);
}

// W16^q = e^{SGN*2pi*i*q/16}
__device__ __forceinline__ float2 w16c(int q, float s) {
    constexpr float C[8] = {1.f, 0.9238795325f, 0.7071067812f, 0.3826834324f,
                            0.f, -0.3826834324f, -0.7071067812f, -0.9238795325f};
    constexpr float S[8] = {0.f, 0.3826834324f, 0.7071067812f, 0.9238795325f,
                            1.f, 0.9238795325f, 0.7071067812f, 0.3826834324f};
    return make_float2(C[q], s*S[q]);
}

template<int SGN>
__device__ __forceinline__ float2 twq(float2 d, int q) {
    if (q == 0) return d;
    if (q == 4) return make_float2((float)(-SGN)*d.y, (float)SGN*d.x);
    return cmulf(d, w16c(q, (float)SGN));
}

// Radix-2 DIF 16-pt DFT: natural-order input, bit-reversed output (bin k at reg REV4[k]).
template<int SGN, bool HZ>
__device__ __forceinline__ void dif16(float2 v[16]) {
    if (HZ) {
        #pragma unroll
        for (int i = 0; i < 8; ++i) {
            float2 a = v[i];
            v[i+8] = twq<SGN>(a, i);
        }
    } else {
        #pragma unroll
        for (int i = 0; i < 8; ++i) {
            float2 a = v[i], b = v[i+8];
            v[i]   = caddf(a,b);
            v[i+8] = twq<SGN>(csubf(a,b), i);
        }
    }
    #pragma unroll
    for (int h = 4; h >= 1; h >>= 1) {
        const int step = 8 / h;
        #pragma unroll
        for (int g = 0; g < 16; g += 2*h) {
            #pragma unroll
            for (int i = 0; i < h; ++i) {
                float2 a = v[g+i], b = v[g+i+h];
                v[g+i]   = caddf(a,b);
                v[g+i+h] = twq<SGN>(csubf(a,b), i*step);
            }
        }
    }
}

// Radix-2 DIT 16-pt DFT: bit-reversed input, natural-order output.
template<int SGN>
__device__ __forceinline__ void dit16(float2 v[16]) {
    #pragma unroll
    for (int h = 1; h <= 8; h <<= 1) {
        const int step = 8 / h;
        #pragma unroll
        for (int g = 0; g < 16; g += 2*h) {
            #pragma unroll
            for (int i = 0; i < h; ++i) {
                float2 a = v[g+i];
                float2 b = twq<SGN>(v[g+i+h], i*step);
                v[g+i]   = caddf(a,b);
                v[g+i+h] = csubf(a,b);
            }
        }
    }
}

__device__ __constant__ int REV4_C[16] = {0,8,4,12,2,10,6,14,1,9,5,13,3,11,7,15};

// Forward 3-level radix-16 FFT of a zero-padded packed real row into LDS Z.
// On exit: position p holds bin drev(p) (base-16 digit reversal), swizzled.
__device__ __forceinline__ void fwd_fft_row(const float2* __restrict__ src, float2* Z, int t) {
    constexpr int REV4[16] = {0,8,4,12,2,10,6,14,1,9,5,13,3,11,7,15};
    float2 v[16], w[16];
    #pragma unroll
    for (int r = 0; r < 8; ++r) v[r] = src[256*r + t];
    dif16<-1, true>(v);
    make_tw(-TWO_PI_F * (float)t / (float)NFFT, w);
    #pragma unroll
    for (int kk = 1; kk < 16; ++kk) v[REV4[kk]] = cmulf(v[REV4[kk]], w[kk]);
    #pragma unroll
    for (int kk = 0; kk < 16; ++kk) Z[swz(256*kk + t)] = v[REV4[kk]];
    __syncthreads();

    const int k1 = t >> 4, m = t & 15;
    const int rb = 256*k1 + m;
    #pragma unroll
    for (int r = 0; r < 16; ++r) v[r] = Z[swz(rb + 16*r)];
    dif16<-1,false>(v);
    make_tw(-TWO_PI_F * (float)m / 256.f, w);
    #pragma unroll
    for (int kk = 1; kk < 16; ++kk) v[REV4[kk]] = cmulf(v[REV4[kk]], w[kk]);
    #pragma unroll
    for (int kk = 0; kk < 16; ++kk) Z[swz(rb + 16*kk)] = v[REV4[kk]];
    __syncthreads();

    const int b3 = t << 4;
    #pragma unroll
    for (int r = 0; r < 16; ++r) v[r] = Z[swz(b3 + r)];
    dif16<-1,false>(v);
    #pragma unroll
    for (int kk = 0; kk < 16; ++kk) Z[swz(b3 + kk)] = v[REV4[kk]];
}

// digit-reversed (base-16) position of bin j, swizzled
__device__ __forceinline__ int binpos(int j) {
    return swz( ((j&15)<<8) | (((j>>4)&15)<<4) | (j>>8) );
}

// ---------------- Kernel A: per-h rfft(k) spectrum -> ws (natural order) ----------------
__global__ __launch_bounds__(THREADS, 4)
void kfft_kernel(const float* __restrict__ k, float2* __restrict__ Kf_all) {
    __shared__ float2 Zk[NFFT];
    const int t  = threadIdx.x;
    const int hh = blockIdx.x;
    const float2* kp = (const float2*)(k + (size_t)hh * L_DIM);

    fwd_fft_row(kp, Zk, t);
    __syncthreads();

    float2* Kf = Kf_all + (size_t)hh * NFFT;
    #pragma unroll
    for (int s = 0; s < 8; ++s) {
        int j = t + 256*s;
        if (j == 0) {
            float2 zk = Zk[0];
            Kf[0] = make_float2(zk.x + zk.y, zk.x - zk.y);   // (A[0], A[M]) both real
            float2 zk2 = Zk[swz(8)];                          // Z[2048], drev(2048)=8
            Kf[2048] = make_float2(zk2.x, -zk2.y);            // A[2048] = conj(Z[2048])
        } else {
            int jm = NFFT - j;
            float2 zkj = Zk[binpos(j)], zkm = Zk[binpos(jm)];
            float sn, cs; __sincosf(-PI_F * (float)j / (float)NFFT, &sn, &cs);
            float2 w = make_float2(cs, sn);
            float2 Ke = make_float2(0.5f*(zkj.x + zkm.x), 0.5f*(zkj.y - zkm.y));
            float2 dk = make_float2(zkj.x - zkm.x, zkj.y + zkm.y);
            float2 Ko = make_float2(0.5f*dk.y, -0.5f*dk.x);
            float2 tk = cmulf(w, Ko);
            Kf[j]  = caddf(Ke, tk);
            Kf[jm] = make_float2(Ke.x - tk.x, -(Ke.y - tk.y));
        }
    }
}

// ---------------- Main kernel: x fwd FFT -> combine w/ global Kf -> inverse ----------------
__global__ __launch_bounds__(THREADS, 4)
void conv_main_kernel(const float* __restrict__ x, const float2* __restrict__ Kf_all,
                      float* __restrict__ out) {
    __shared__ float2 Zx[NFFT];
    constexpr int REV4[16] = {0,8,4,12,2,10,6,14,1,9,5,13,3,11,7,15};

    const int t  = threadIdx.x;
    const int wg = blockIdx.x;
    const int hh = wg & (H_DIM - 1);
    const int b  = wg >> 10;

    const float2* xp = (const float2*)(x + ((size_t)(b*H_DIM + hh)) * L_DIM);
    const float2* Kf = Kf_all + (size_t)hh * NFFT;

    fwd_fft_row(xp, Zx, t);

    // prefetch K spectrum while the barrier drains
    float2 kfj[8], kfm[8], kf2;
    #pragma unroll
    for (int s = 0; s < 8; ++s) {
        int j = t + 256*s;
        kfj[s] = Kf[j];
        kfm[s] = Kf[(NFFT - j) & (NFFT - 1)];
    }
    kf2 = Kf[2048];
    __syncthreads();

    // combine: unpack x half-complex bins, multiply by Kf, repack in place
    #pragma unroll
    for (int s = 0; s < 8; ++s) {
        int j = t + 256*s;
        if (j == 0) {
            float2 zx = Zx[0];
            float ax0 = zx.x + zx.y, axM = zx.x - zx.y;
            float y0 = ax0 * kfj[0].x, yM = axM * kfj[0].y;
            Zx[0] = make_float2(0.5f*(y0 + yM), 0.5f*(y0 - yM));
            int p2 = swz(8);
            float2 zx2 = Zx[p2];
            Zx[p2] = cmulf(zx2, make_float2(kf2.x, -kf2.y));  // Zx*conj(A_k)=Zx*Zk
        } else {
            int jm = NFFT - j;
            int pj = binpos(j), pm = binpos(jm);
            float2 zxj = Zx[pj], zxm = Zx[pm];

            float sn, cs; __sincosf(-PI_F * (float)j / (float)NFFT, &sn, &cs);
            float2 w = make_float2(cs, sn);

            float2 Xe = make_float2(0.5f*(zxj.x + zxm.x), 0.5f*(zxj.y - zxm.y));
            float2 dx = make_float2(zxj.x - zxm.x, zxj.y + zxm.y);
            float2 Xo = make_float2(0.5f*dx.y, -0.5f*dx.x);
            float2 tx = cmulf(w, Xo);
            float2 Axj = caddf(Xe, tx);
            float2 Axm = make_float2(Xe.x - tx.x, -(Xe.y - tx.y));

            float2 Yj = cmulf(Axj, kfj[s]);
            float2 Ym = cmulf(Axm, kfm[s]);

            float2 u  = make_float2(0.5f*(Yj.x + Ym.x), 0.5f*(Yj.y - Ym.y));
            float2 dd = make_float2(Yj.x - Ym.x, Yj.y + Ym.y);
            float2 wc = make_float2(w.x, -w.y);
            float2 vv = cmulf(wc, dd);
            vv.x *= 0.5f; vv.y *= 0.5f;
            Zx[pj] = make_float2(u.x - vv.y, u.y + vv.x);
            Zx[pm] = make_float2(u.x + vv.y, -(u.y - vv.x));
        }
    }
    __syncthreads();

    float2 vx[16], w[16];
    const int k1 = t >> 4, m = t & 15;
    const int rb = 256*k1 + m;
    const int b3 = t << 4;

    // inverse level A: contiguous 16-blocks, pure iDFT
    #pragma unroll
    for (int r = 0; r < 16; ++r) vx[REV4[r]] = Zx[swz(b3 + r)];
    dit16<1>(vx);
    #pragma unroll
    for (int mm = 0; mm < 16; ++mm) Zx[swz(b3 + mm)] = vx[mm];
    __syncthreads();

    // inverse level B: untwiddle then iDFT over stride-16
    make_tw(TWO_PI_F * (float)m / 256.f, w);
    #pragma unroll
    for (int kk = 0; kk < 16; ++kk) {
        float2 val = Zx[swz(rb + 16*kk)];
        if (kk > 0) val = cmulf(val, w[kk]);
        vx[REV4[kk]] = val;
    }
    dit16<1>(vx);
    #pragma unroll
    for (int r = 0; r < 16; ++r) Zx[swz(rb + 16*r)] = vx[r];
    __syncthreads();

    // inverse level C: untwiddle, iDFT over stride-256, store first 4096 reals
    make_tw(TWO_PI_F * (float)t / (float)NFFT, w);
    #pragma unroll
    for (int kk = 0; kk < 16; ++kk) {
        float2 val = Zx[swz(256*kk + t)];
        if (kk > 0) val = cmulf(val, w[kk]);
        vx[REV4[kk]] = val;
    }
    dit16<1>(vx);
    float2* op = (float2*)(out + ((size_t)(b*H_DIM + hh)) * L_DIM);
    const float sc = 1.f / (float)NFFT;
    #pragma unroll
    for (int n1 = 0; n1 < 8; ++n1) {
        float2 z = vx[n1];
        op[256*n1 + t] = make_float2(z.x*sc, z.y*sc);
    }
}

// ---------------- Fallback (R2, known-good): used if ws too small ----------------
__global__ __launch_bounds__(THREADS, 2)
void fftconv_fallback(const float* __restrict__ x, const float* __restrict__ k,
                      float* __restrict__ out) {
    __shared__ float2 Zx[NFFT];
    __shared__ float2 Zk[NFFT];
    constexpr int REV4[16] = {0,8,4,12,2,10,6,14,1,9,5,13,3,11,7,15};

    const int t  = threadIdx.x;
    const int wg = blockIdx.x;
    const int hh = wg & (H_DIM - 1);
    const int b  = wg >> 10;

    const float2* xp = (const float2*)(x + ((size_t)(b*H_DIM + hh)) * L_DIM);
    const float2* kp = (const float2*)(k + (size_t)hh * L_DIM);

    fwd_fft_row(xp, Zx, t);
    __syncthreads();
    fwd_fft_row(kp, Zk, t);
    __syncthreads();

    #pragma unroll
    for (int s = 0; s < 8; ++s) {
        int j = t + 256*s;
        if (j == 0) {
            float2 zx = Zx[0], zk = Zk[0];
            float ax0 = zx.x + zx.y, axM = zx.x - zx.y;
            float ak0 = zk.x + zk.y, akM = zk.x - zk.y;
            float y0 = ax0*ak0, yM = axM*akM;
            Zx[0] = make_float2(0.5f*(y0+yM), 0.5f*(y0-yM));
            int p2 = swz(8);
            Zx[p2] = cmulf(Zx[p2], Zk[p2]);
        } else {
            int jm = NFFT - j;
            int pj = binpos(j), pm = binpos(jm);
            float2 zxj = Zx[pj], zxm = Zx[pm];
            float2 zkj = Zk[pj], zkm = Zk[pm];
            float sn, cs; __sincosf(-PI_F * (float)j / (float)NFFT, &sn, &cs);
            float2 w = make_float2(cs, sn);
            float2 Xe = make_float2(0.5f*(zxj.x + zxm.x), 0.5f*(zxj.y - zxm.y));
            float2 dx = make_float2(zxj.x - zxm.x, zxj.y + zxm.y);
            float2 Xo = make_float2(0.5f*dx.y, -0.5f*dx.x);
            float2 tx = cmulf(w, Xo);
            float2 Axj = caddf(Xe, tx);
            float2 Axm = make_float2(Xe.x - tx.x, -(Xe.y - tx.y));
            float2 Ke = make_float2(0.5f*(zkj.x + zkm.x), 0.5f*(zkj.y - zkm.y));
            float2 dk = make_float2(zkj.x - zkm.x, zkj.y + zkm.y);
            float2 Ko = make_float2(0.5f*dk.y, -0.5f*dk.x);
            float2 tk = cmulf(w, Ko);
            float2 Akj = caddf(Ke, tk);
            float2 Akm = make_float2(Ke.x - tk.x, -(Ke.y - tk.y));
            float2 Yj = cmulf(Axj, Akj);
            float2 Ym = cmulf(Axm, Akm);
            float2 u  = make_float2(0.5f*(Yj.x + Ym.x), 0.5f*(Yj.y - Ym.y));
            float2 dd = make_float2(Yj.x - Ym.x, Yj.y + Ym.y);
            float2 wc = make_float2(w.x, -w.y);
            float2 vv = cmulf(wc, dd);
            vv.x *= 0.5f; vv.y *= 0.5f;
            Zx[pj] = make_float2(u.x - vv.y, u.y + vv.x);
            Zx[pm] = make_float2(u.x + vv.y, -(u.y - vv.x));
        }
    }
    __syncthreads();

    float2 vx[16], w[16];
    const int k1 = t >> 4, m = t & 15;
    const int rb = 256*k1 + m;
    const int b3 = t << 4;

    #pragma unroll
    for (int r = 0; r < 16; ++r) vx[REV4[r]] = Zx[swz(b3 + r)];
    dit16<1>(vx);
    #pragma unroll
    for (int mm = 0; mm < 16; ++mm) Zx[swz(b3 + mm)] = vx[mm];
    __syncthreads();

    make_tw(TWO_PI_F * (float)m / 256.f, w);
    #pragma unroll
    for (int kk = 0; kk < 16; ++kk) {
        float2 val = Zx[swz(rb + 16*kk)];
        if (kk > 0) val = cmulf(val, w[kk]);
        vx[REV4[kk]] = val;
    }
    dit16<1>(vx);
    #pragma unroll
    for (int r = 0; r < 16; ++r) Zx[swz(rb + 16*r)] = vx[r];
    __syncthreads();

    make_tw(TWO_PI_F * (float)t / (float)NFFT, w);
    #pragma unroll
    for (int kk = 0; kk < 16; ++kk) {
        float2 val = Zx[swz(256*kk + t)];
        if (kk > 0) val = cmulf(val, w[kk]);
        vx[REV4[kk]] = val;
    }
    dit16<1>(vx);
    float2* op = (float2*)(out + ((size_t)(b*H_DIM + hh)) * L_DIM);
    const float sc = 1.f / (float)NFFT;
    #pragma unroll
    for (int n1 = 0; n1 < 8; ++n1) {
        float2 z = vx[n1];
        op[256*n1 + t] = make_float2(z.x*sc, z.y*sc);
    }
}

extern "C" void kernel_launch(void* const* d_in, const int* in_sizes, int n_in,
                              void* d_out, int out_size, void* d_ws, size_t ws_size,
                              hipStream_t stream) {
    const float* x = (const float*)d_in[0];
    const float* k = (const float*)d_in[1];
    float* out = (float*)d_out;
    const size_t need = (size_t)H_DIM * NFFT * sizeof(float2);   // 32 MB
    if (ws_size >= need) {
        float2* Kf = (float2*)d_ws;
        kfft_kernel<<<dim3(H_DIM), dim3(THREADS), 0, stream>>>(k, Kf);
        conv_main_kernel<<<dim3(B_DIM * H_DIM), dim3(THREADS), 0, stream>>>(x, Kf, out);
    } else {
        fftconv_fallback<<<dim3(B_DIM * H_DIM), dim3(THREADS), 0, stream>>>(x, k, out);
    }
}